// Round 1
// baseline (111.743 us; speedup 1.0000x reference)
//
#include <hip/hip_runtime.h>
#include <hip/hip_bf16.h>
#include <math.h>

#define N 64
#define BATCH 2
#define PLANE (N * N)            // 4096
#define VOL (BATCH * N * N * N)  // 524288
#define BIGF 1e8f
#define LP 65                    // padded LDS stride
#define FBIG 3.4e38f

// ---------------------------------------------------------------------------
// Workspace layout (floats):
//   [0,VOL)      TDM1      (sqrt EDT of lz1)
//   [VOL,2V)     BND1      (boundary of mask1, 0/1)
//   [2V,3V)      TDM2
//   [3V,4V)      BND2
//   [4V,5V)      TSD1      (stage2 output; slot reused as stage1 mid set0)
//   [5V,6V)      TSD2      (stage1 mid set1)
//   [6V,7V)      stage1 mid set2 / stage2 mid m0
//   [7V,8V)      stage1 mid set3 / stage2 mid m1
//   [8V, +8)     accumulators
// ---------------------------------------------------------------------------

// Kernel A: binarize + Y-pass + Z-pass for one (b,x) plane. set picks source.
__global__ __launch_bounds__(256) void edt_yz(const int* __restrict__ mmap,
                                              float* __restrict__ ws,
                                              int stage) {
  __shared__ float A[N][LP];
  __shared__ float Bm[N][LP];
  const int set = blockIdx.x >> 7;
  const int plane = blockIdx.x & 127;
  const int b = plane >> 6;
  const int x = plane & 63;
  const int t = threadIdx.x;
  const int lane = t & 63;
  const int w = t >> 6;
  const size_t planeBase = (size_t)(b * N + x) * PLANE;

  if (stage == 1) {
    // set0: lz1 tdm-mode, set1: lz1 b-mode, set2: lz2 tdm, set3: lz2 b
    const unsigned mask = (set < 2) ? 0x17u : 0x13u;  // {0,1,2,4} / {0,1,4}
    const int bmode = set & 1;
    #pragma unroll
    for (int k = 0; k < 16; ++k) {
      const int e = t + 256 * k;
      const int v = mmap[planeBase + e];
      const int lz = (mask >> v) & 1;
      A[e >> 6][e & 63] = ((lz ^ bmode) != 0) ? BIGF : 0.f;
    }
  } else {
    // level_zero_inner = (tdm==0 && bnd==0); EDT input: BIG where level>0
    const float* tdm = ws + (size_t)set * 2 * VOL;
    const float* bnd = tdm + VOL;
    #pragma unroll
    for (int k = 0; k < 16; ++k) {
      const int e = t + 256 * k;
      const float td = tdm[planeBase + e];
      const float bd = bnd[planeBase + e];
      A[e >> 6][e & 63] = (td == 0.f && bd == 0.f) ? BIGF : 0.f;
    }
  }
  __syncthreads();

  {  // Y-pass: Bm[y][z] = min_j A[j][z] + (y-j)^2 ; z = lane, y = w + 4*q
    float acc[16], del[16];
    #pragma unroll
    for (int q = 0; q < 16; ++q) { acc[q] = FBIG; del[q] = (float)(w + 4 * q); }
    #pragma unroll 4
    for (int j = 0; j < N; ++j) {
      const float fj = A[j][lane];
      #pragma unroll
      for (int q = 0; q < 16; ++q) {
        acc[q] = fminf(acc[q], fmaf(del[q], del[q], fj));
        del[q] -= 1.f;
      }
    }
    #pragma unroll
    for (int q = 0; q < 16; ++q) Bm[w + 4 * q][lane] = acc[q];
  }
  __syncthreads();

  {  // Z-pass: A[y][z] = min_j Bm[y][j] + (z-j)^2 ; y = lane, z = w + 4*q
    float acc[16], del[16];
    #pragma unroll
    for (int q = 0; q < 16; ++q) { acc[q] = FBIG; del[q] = (float)(w + 4 * q); }
    #pragma unroll 4
    for (int j = 0; j < N; ++j) {
      const float fj = Bm[lane][j];
      #pragma unroll
      for (int q = 0; q < 16; ++q) {
        acc[q] = fminf(acc[q], fmaf(del[q], del[q], fj));
        del[q] -= 1.f;
      }
    }
    #pragma unroll
    for (int q = 0; q < 16; ++q) A[lane][w + 4 * q] = acc[q];
  }
  __syncthreads();

  float* mid = ws + (size_t)((stage == 1 ? 4 : 6) + set) * VOL;
  #pragma unroll
  for (int k = 0; k < 16; ++k) {
    const int e = t + 256 * k;
    mid[planeBase + e] = A[e >> 6][e & 63];
  }
}

// Kernel B: X-pass over (X,Z) planes at fixed (b,y), fused finalization.
__global__ __launch_bounds__(256) void edt_x_final(float* __restrict__ ws,
                                                   int stage) {
  __shared__ float A[N][LP];
  const int set = blockIdx.x >> 7;
  const int plane = blockIdx.x & 127;
  const int b = plane >> 6;
  const int y = plane & 63;
  const int t = threadIdx.x;
  const int lane = t & 63;  // z
  const int w = t >> 6;

  const float* in = ws + (size_t)((stage == 1 ? 4 : 6) + set) * VOL;
  #pragma unroll
  for (int k = 0; k < 16; ++k) {
    const int e = t + 256 * k;
    const int xx = e >> 6, z = e & 63;
    A[xx][z] = in[(size_t)(b * N + xx) * PLANE + y * N + z];
  }
  __syncthreads();

  float acc[16], del[16];
  #pragma unroll
  for (int q = 0; q < 16; ++q) { acc[q] = FBIG; del[q] = (float)(w + 4 * q); }
  #pragma unroll 4
  for (int j = 0; j < N; ++j) {
    const float fj = A[j][lane];
    #pragma unroll
    for (int q = 0; q < 16; ++q) {
      acc[q] = fminf(acc[q], fmaf(del[q], del[q], fj));
      del[q] -= 1.f;
    }
  }

  const int z = lane;
  if (stage == 1) {
    if ((set & 1) == 0) {  // tdm output (sqrt)
      float* tdm = ws + (size_t)(set >> 1) * 2 * VOL;
      #pragma unroll
      for (int q = 0; q < 16; ++q) {
        const int x = w + 4 * q;
        tdm[(size_t)(b * N + x) * PLANE + y * N + z] = sqrtf(acc[q]);
      }
    } else {  // boundary output: (b_sq == 1)
      float* bnd = ws + (size_t)(set >> 1) * 2 * VOL + VOL;
      #pragma unroll
      for (int q = 0; q < 16; ++q) {
        const int x = w + 4 * q;
        bnd[(size_t)(b * N + x) * PLANE + y * N + z] =
            (acc[q] == 1.0f) ? 1.f : 0.f;
      }
    }
  } else {  // tsd = tdm - sqrt(e)
    const float* tdm = ws + (size_t)set * 2 * VOL;
    float* tsd = ws + (size_t)(4 + set) * VOL;
    #pragma unroll
    for (int q = 0; q < 16; ++q) {
      const int x = w + 4 * q;
      const size_t idx = (size_t)(b * N + x) * PLANE + y * N + z;
      tsd[idx] = tdm[idx] - sqrtf(acc[q]);
    }
  }
}

__global__ void init_acc(float* acc) {
  const int i = threadIdx.x;
  if (i < 8) acc[i] = 0.f;
}

__global__ __launch_bounds__(256) void reduce_k(const float* __restrict__ ws,
                                                float* __restrict__ acc) {
  const float* bnd1 = ws + (size_t)VOL;
  const float* bnd2 = ws + (size_t)3 * VOL;
  const float* tsd1 = ws + (size_t)4 * VOL;
  const float* tsd2 = ws + (size_t)5 * VOL;
  float sb1 = 0.f, sb2 = 0.f, shi = 0.f, sho = 0.f, mhi = 0.f, mho = 0.f;
  for (int i = blockIdx.x * blockDim.x + threadIdx.x; i < VOL;
       i += gridDim.x * blockDim.x) {
    const float b1 = bnd1[i], b2 = bnd2[i], t1 = tsd1[i], t2 = tsd2[i];
    const float hi = b1 * fabsf(t2);  // hausdorff_inner element
    const float ho = b2 * fabsf(t1);  // hausdorff_outer element
    sb1 += b1; sb2 += b2; shi += hi; sho += ho;
    mhi = fmaxf(mhi, hi); mho = fmaxf(mho, ho);
  }
  #pragma unroll
  for (int o = 32; o > 0; o >>= 1) {
    sb1 += __shfl_down(sb1, o);
    sb2 += __shfl_down(sb2, o);
    shi += __shfl_down(shi, o);
    sho += __shfl_down(sho, o);
    mhi = fmaxf(mhi, __shfl_down(mhi, o));
    mho = fmaxf(mho, __shfl_down(mho, o));
  }
  if ((threadIdx.x & 63) == 0) {
    atomicAdd(&acc[0], sb1);
    atomicAdd(&acc[1], sb2);
    atomicAdd(&acc[2], shi);
    atomicAdd(&acc[3], sho);
    atomicMax((int*)&acc[4], __float_as_int(mhi));  // values >= 0: int order ok
    atomicMax((int*)&acc[5], __float_as_int(mho));
  }
}

__global__ void final_k(const float* __restrict__ acc, float* __restrict__ out) {
  if (threadIdx.x == 0) {
    const float him = acc[2] / acc[0];
    const float hom = acc[3] / acc[1];
    out[0] = him;
    out[1] = acc[4];
    out[2] = hom;
    out[3] = acc[5];
    out[4] = (him - 2.f) * (him - 2.f) + (hom - 2.f) * (hom - 2.f);
  }
}

extern "C" void kernel_launch(void* const* d_in, const int* in_sizes, int n_in,
                              void* d_out, int out_size, void* d_ws,
                              size_t ws_size, hipStream_t stream) {
  (void)in_sizes; (void)n_in; (void)out_size; (void)ws_size;
  const int* mmap = (const int*)d_in[0];
  float* ws = (float*)d_ws;
  float* acc = ws + (size_t)8 * VOL;
  float* out = (float*)d_out;

  init_acc<<<1, 64, 0, stream>>>(acc);
  // Stage 1: 4 independent EDTs (tdm1, b1, tdm2, b2)
  edt_yz<<<4 * BATCH * N, 256, 0, stream>>>(mmap, ws, 1);
  edt_x_final<<<4 * BATCH * N, 256, 0, stream>>>(ws, 1);
  // Stage 2: 2 dependent EDTs (level-zero of each mask) -> tsd
  edt_yz<<<2 * BATCH * N, 256, 0, stream>>>(mmap, ws, 2);
  edt_x_final<<<2 * BATCH * N, 256, 0, stream>>>(ws, 2);
  // Reduction to 5 scalars
  reduce_k<<<128, 256, 0, stream>>>(ws, acc);
  final_k<<<1, 64, 0, stream>>>(acc, out);
}

// Round 2
// 55.175 us; speedup vs baseline: 2.0253x; 2.0253x over previous
//
#include <hip/hip_runtime.h>
#include <hip/hip_bf16.h>
#include <math.h>

#define N 64
#define BATCH 2
#define PLANE (N * N)            // 4096
#define VOL (BATCH * N * N * N)  // 524288
#define BIGF 1e8f
#define LP 65                    // padded LDS stride
#define FBIG 3.4e38f
#define MASK1 0x17u              // labels {0,1,2,4}
#define MASK2 0x13u              // labels {0,1,4}

// ---------------------------------------------------------------------------
// Workspace (floats):
//   slot s in [0,6): mid_s  (Y+Z passed squared-EDT, per set)
//     after K2 (in-place): slot0=tdm1, slot1=bnd1, slot2=tdm2, slot3=bnd2
//   [6*VOL, +8): accumulators
//     acc[0]=sum bnd1, acc[1]=sum bnd2, acc[2]=sum hi, acc[3]=sum ho,
//     acc[4]=max hi,   acc[5]=max ho
// Sets: 0=tdm1, 1=b1, 2=tdm2, 3=b2, 4=levelzero1, 5=levelzero2
// ---------------------------------------------------------------------------

// K1: binarize (or stencil) + exact nearest-zero scan along Y + brute Z-pass.
__global__ __launch_bounds__(256) void edt_pass12(const int* __restrict__ mmap,
                                                  float* __restrict__ ws) {
  __shared__ float Bm[N][LP];    // scan output (y,z)
  __shared__ float Ao[N][LP];    // z-pass output staging
  __shared__ int lastZ[4][N];
  __shared__ int firstZ[4][N];
  const int set = blockIdx.x >> 7;
  const int plane = blockIdx.x & 127;
  const int b = plane >> 6, x = plane & 63;
  const int t = threadIdx.x;
  const int z = t & 63, c = t >> 6;  // chunk c covers y in [16c,16c+16)
  const size_t planeBase = (size_t)(b * N + x) * PLANE;

  if (blockIdx.x == 0 && t < 8) ws[(size_t)6 * VOL + t] = 0.f;  // zero acc
  if (t < 8) ws[(size_t)6 * VOL + t] = 0.f;  // every block: benign dup write

  // ---- build zero-site bitmask for y = 16c+k ----
  const unsigned lmask = (set == 2 || set == 3 || set == 5) ? MASK2 : MASK1;
  unsigned zm = 0;
  if (set < 4) {
    const int want = set & 1;  // zero-site iff lz == want^? set0/2: lz==0; set1/3: lz==1
    #pragma unroll
    for (int k = 0; k < 16; ++k) {
      const int y = 16 * c + k;
      const int lz = (lmask >> mmap[planeBase + y * N + z]) & 1;
      const int zb = (set & 1) ? lz : (lz ^ 1);
      zm |= (unsigned)zb << k;
      (void)want;
    }
  } else {
    // level-zero EDT input: zero-site iff lz(self) or any 6-neighbor lz
    #pragma unroll
    for (int k = 0; k < 16; ++k) {
      const int y = 16 * c + k;
      const size_t e = planeBase + y * N + z;
      int zr = (lmask >> mmap[e]) & 1;
      if (x > 0)  zr |= (lmask >> mmap[e - PLANE]) & 1;
      if (x < 63) zr |= (lmask >> mmap[e + PLANE]) & 1;
      if (y > 0)  zr |= (lmask >> mmap[e - N]) & 1;
      if (y < 63) zr |= (lmask >> mmap[e + N]) & 1;
      if (z > 0)  zr |= (lmask >> mmap[e - 1]) & 1;
      if (z < 63) zr |= (lmask >> mmap[e + 1]) & 1;
      zm |= (unsigned)zr << k;
    }
  }

  // ---- exact nearest-zero scan along y (two-sided, chunk carries) ----
  lastZ[c][z]  = zm ? (16 * c + 31 - __clz(zm)) : -1000;
  firstZ[c][z] = zm ? (16 * c + __ffs(zm) - 1) : 2000;
  __syncthreads();
  int carryL = -1000, carryR = 2000;
  #pragma unroll
  for (int cc = 0; cc < 4; ++cc) {
    const int lv = lastZ[cc][z], fv = firstZ[cc][z];
    if (cc < c) carryL = max(carryL, lv);
    if (cc > c) carryR = min(carryR, fv);
  }
  int dl[16];
  {
    int last = carryL;
    #pragma unroll
    for (int k = 0; k < 16; ++k) {
      const int y = 16 * c + k;
      if ((zm >> k) & 1) last = y;
      dl[k] = y - last;
    }
  }
  {
    int first = carryR;
    #pragma unroll
    for (int k = 15; k >= 0; --k) {
      const int y = 16 * c + k;
      if ((zm >> k) & 1) first = y;
      const int dr = first - y;
      const int d = min(dl[k], dr);
      Bm[y][z] = (d > 63) ? BIGF : (float)(d * d);
    }
  }
  __syncthreads();

  // ---- Z-pass (brute parabola min): out[y][zz] = min_j Bm[y][j]+(zz-j)^2 ----
  {
    const int y = t & 63, w = t >> 6;
    float acc[16], del[16];
    #pragma unroll
    for (int q = 0; q < 16; ++q) { acc[q] = FBIG; del[q] = (float)(w + 4 * q); }
    #pragma unroll 4
    for (int j = 0; j < N; ++j) {
      const float fj = Bm[y][j];
      #pragma unroll
      for (int q = 0; q < 16; ++q) {
        acc[q] = fminf(acc[q], fmaf(del[q], del[q], fj));
        del[q] -= 1.f;
      }
    }
    #pragma unroll
    for (int q = 0; q < 16; ++q) Ao[y][w + 4 * q] = acc[q];
  }
  __syncthreads();

  float* mid = ws + (size_t)set * VOL;
  #pragma unroll
  for (int k = 0; k < 16; ++k) {
    const int e = t + 256 * k;
    mid[planeBase + e] = Ao[e >> 6][e & 63];
  }
}

// K2: X-pass for sets 0..3, in-place (mid -> tdm/bnd), fused boundary sums.
__global__ __launch_bounds__(256) void edt_x1(float* __restrict__ ws) {
  __shared__ float A[N][LP];
  __shared__ float red[4];
  const int set = blockIdx.x >> 7;
  const int plane = blockIdx.x & 127;
  const int b = plane >> 6, y = plane & 63;
  const int t = threadIdx.x;
  const int lane = t & 63, w = t >> 6;  // lane = z

  float* vol = ws + (size_t)set * VOL;
  #pragma unroll
  for (int k = 0; k < 16; ++k) {
    const int e = t + 256 * k;
    const int xx = e >> 6, z = e & 63;
    A[xx][z] = vol[(size_t)(b * N + xx) * PLANE + y * N + z];
  }
  __syncthreads();

  float acc[16], del[16];
  #pragma unroll
  for (int q = 0; q < 16; ++q) { acc[q] = FBIG; del[q] = (float)(w + 4 * q); }
  #pragma unroll 4
  for (int j = 0; j < N; ++j) {
    const float fj = A[j][lane];
    #pragma unroll
    for (int q = 0; q < 16; ++q) {
      acc[q] = fminf(acc[q], fmaf(del[q], del[q], fj));
      del[q] -= 1.f;
    }
  }

  const int z = lane;
  if ((set & 1) == 0) {  // tdm = sqrt(e)
    #pragma unroll
    for (int q = 0; q < 16; ++q) {
      const int xx = w + 4 * q;
      vol[(size_t)(b * N + xx) * PLANE + y * N + z] = sqrtf(acc[q]);
    }
  } else {  // boundary = (e == 1), plus block sum -> acc[set>>1]
    float sb = 0.f;
    #pragma unroll
    for (int q = 0; q < 16; ++q) {
      const int xx = w + 4 * q;
      const float bd = (acc[q] == 1.0f) ? 1.f : 0.f;
      vol[(size_t)(b * N + xx) * PLANE + y * N + z] = bd;
      sb += bd;
    }
    #pragma unroll
    for (int o = 32; o > 0; o >>= 1) sb += __shfl_down(sb, o);
    if (lane == 0) red[w] = sb;
    __syncthreads();
    if (t == 0) {
      float* accp = ws + (size_t)6 * VOL;
      atomicAdd(&accp[set >> 1], red[0] + red[1] + red[2] + red[3]);
    }
  }
}

// K3: X-pass for sets 4,5 + fused hausdorff reduction (tsd never stored).
__global__ __launch_bounds__(256) void edt_x2(float* __restrict__ ws) {
  __shared__ float A[N][LP];
  __shared__ float redS[4];
  __shared__ float redM[4];
  const int m = blockIdx.x >> 7;  // 0: tsd1 (pairs bnd2), 1: tsd2 (pairs bnd1)
  const int plane = blockIdx.x & 127;
  const int b = plane >> 6, y = plane & 63;
  const int t = threadIdx.x;
  const int lane = t & 63, w = t >> 6;  // lane = z

  const float* mid = ws + (size_t)(4 + m) * VOL;
  #pragma unroll
  for (int k = 0; k < 16; ++k) {
    const int e = t + 256 * k;
    const int xx = e >> 6, z = e & 63;
    A[xx][z] = mid[(size_t)(b * N + xx) * PLANE + y * N + z];
  }
  __syncthreads();

  float acc[16], del[16];
  #pragma unroll
  for (int q = 0; q < 16; ++q) { acc[q] = FBIG; del[q] = (float)(w + 4 * q); }
  #pragma unroll 4
  for (int j = 0; j < N; ++j) {
    const float fj = A[j][lane];
    #pragma unroll
    for (int q = 0; q < 16; ++q) {
      acc[q] = fminf(acc[q], fmaf(del[q], del[q], fj));
      del[q] -= 1.f;
    }
  }

  const float* tdm = ws + (size_t)(m * 2) * VOL;       // tdm of same mask
  const float* bndP = ws + (size_t)(m == 0 ? 3 : 1) * VOL;  // partner boundary
  const int z = lane;
  float hsum = 0.f, hmax = 0.f;
  #pragma unroll
  for (int q = 0; q < 16; ++q) {
    const int xx = w + 4 * q;
    const size_t idx = (size_t)(b * N + xx) * PLANE + y * N + z;
    const float tsd = tdm[idx] - sqrtf(acc[q]);
    const float h = bndP[idx] * fabsf(tsd);
    hsum += h;
    hmax = fmaxf(hmax, h);
  }
  #pragma unroll
  for (int o = 32; o > 0; o >>= 1) {
    hsum += __shfl_down(hsum, o);
    hmax = fmaxf(hmax, __shfl_down(hmax, o));
  }
  if (lane == 0) { redS[w] = hsum; redM[w] = hmax; }
  __syncthreads();
  if (t == 0) {
    float* accp = ws + (size_t)6 * VOL;
    const float s = redS[0] + redS[1] + redS[2] + redS[3];
    const float mx = fmaxf(fmaxf(redM[0], redM[1]), fmaxf(redM[2], redM[3]));
    // m==0 -> h_outer (acc[3], acc[5]); m==1 -> h_inner (acc[2], acc[4])
    atomicAdd(&accp[m == 0 ? 3 : 2], s);
    atomicMax((int*)&accp[m == 0 ? 5 : 4], __float_as_int(mx));  // vals >= 0
  }
}

__global__ void final_k(const float* __restrict__ ws, float* __restrict__ out) {
  if (threadIdx.x == 0) {
    const float* acc = ws + (size_t)6 * VOL;
    const float him = acc[2] / acc[0];
    const float hom = acc[3] / acc[1];
    out[0] = him;
    out[1] = acc[4];
    out[2] = hom;
    out[3] = acc[5];
    out[4] = (him - 2.f) * (him - 2.f) + (hom - 2.f) * (hom - 2.f);
  }
}

extern "C" void kernel_launch(void* const* d_in, const int* in_sizes, int n_in,
                              void* d_out, int out_size, void* d_ws,
                              size_t ws_size, hipStream_t stream) {
  (void)in_sizes; (void)n_in; (void)out_size; (void)ws_size;
  const int* mmap = (const int*)d_in[0];
  float* ws = (float*)d_ws;
  float* out = (float*)d_out;

  edt_pass12<<<6 * BATCH * N, 256, 0, stream>>>(mmap, ws);  // all 6 Y+Z passes
  edt_x1<<<4 * BATCH * N, 256, 0, stream>>>(ws);            // X-pass + tdm/bnd + Σbnd
  edt_x2<<<2 * BATCH * N, 256, 0, stream>>>(ws);            // X-pass + hausdorff reduce
  final_k<<<1, 64, 0, stream>>>(ws, out);
}

// Round 3
// 46.257 us; speedup vs baseline: 2.4157x; 1.1928x over previous
//
#include <hip/hip_runtime.h>
#include <hip/hip_bf16.h>
#include <math.h>

#define N 64
#define BATCH 2
#define PLANE (N * N)            // 4096
#define VOL (BATCH * N * N * N)  // 524288
#define BIGF 1e8f
#define LP 65                    // padded LDS stride
#define FBIG 3.4e38f
#define MASK1 0x17u              // labels {0,1,2,4}
#define MASK2 0x13u              // labels {0,1,4}

// ---------------------------------------------------------------------------
// Workspace:
//   floats [0, 4*VOL): mid slots — set0=tdm1, set1=tdm2, set2=lz0_1, set3=lz0_2
//   floats [4*VOL, 4*VOL+8): accumulators
//     acc[0]=sum bnd1, acc[1]=sum bnd2, acc[2]=sum hi, acc[3]=sum ho,
//     acc[4]=max hi,   acc[5]=max ho
//   uint64 at (ws + 4*VOL + 16): bndbits[2][2*64*64]  (y-bitmask per (b,x,z))
//     region 0 = mask1 boundary, region 1 = mask2 boundary
// ---------------------------------------------------------------------------

// K1: binarize/stencil + exact nearest-zero Y-scan + Z-envelope (2-op inner).
__global__ __launch_bounds__(256) void edt_yz(const int* __restrict__ mmap,
                                              float* __restrict__ ws) {
  __shared__ float Bm[N][LP];    // y-scan output, +z^2 folded
  __shared__ float Ao[N][LP];    // z-pass output staging
  __shared__ int lastZ[4][N];
  __shared__ int firstZ[4][N];
  __shared__ unsigned short bb[4][N];
  const int set = blockIdx.x >> 7;
  const int plane = blockIdx.x & 127;
  const int b = plane >> 6, x = plane & 63;
  const int t = threadIdx.x;
  const int z = t & 63, c = t >> 6;  // chunk c: y in [16c, 16c+16)
  const size_t planeBase = (size_t)(b * N + x) * PLANE;

  if (t < 8) ws[(size_t)4 * VOL + t] = 0.f;  // zero acc (dup write, pre-K2)

  const unsigned lmask = (set & 1) ? MASK2 : MASK1;
  unsigned zm = 0, bm = 0;
  if (set < 2) {
    // tdm EDT: zero-site iff lz == 0
    #pragma unroll
    for (int k = 0; k < 16; ++k) {
      const int y = 16 * c + k;
      const int lz = (lmask >> mmap[planeBase + y * N + z]) & 1;
      zm |= (unsigned)(lz ^ 1) << k;
    }
  } else {
    // level-zero EDT: zero-site iff lz or 6-neighbor lz; bnd = nbr & !lz
    #pragma unroll
    for (int k = 0; k < 16; ++k) {
      const int y = 16 * c + k;
      const size_t e = planeBase + y * N + z;
      const int self = (lmask >> mmap[e]) & 1;
      int nb = 0;
      if (x > 0)  nb |= (lmask >> mmap[e - PLANE]) & 1;
      if (x < 63) nb |= (lmask >> mmap[e + PLANE]) & 1;
      if (y > 0)  nb |= (lmask >> mmap[e - N]) & 1;
      if (y < 63) nb |= (lmask >> mmap[e + N]) & 1;
      if (z > 0)  nb |= (lmask >> mmap[e - 1]) & 1;
      if (z < 63) nb |= (lmask >> mmap[e + 1]) & 1;
      zm |= (unsigned)(self | nb) << k;
      bm |= (unsigned)(nb & (self ^ 1)) << k;
    }
  }

  lastZ[c][z]  = zm ? (16 * c + 31 - __clz(zm)) : -1000;
  firstZ[c][z] = zm ? (16 * c + __ffs(zm) - 1) : 2000;
  if (set >= 2) bb[c][z] = (unsigned short)bm;
  __syncthreads();

  // boundary bitmask writeout (mask region set-2)
  if (set >= 2 && t < N) {
    unsigned long long v = (unsigned long long)bb[0][t] |
                           ((unsigned long long)bb[1][t] << 16) |
                           ((unsigned long long)bb[2][t] << 32) |
                           ((unsigned long long)bb[3][t] << 48);
    unsigned long long* bits =
        (unsigned long long*)(ws + (size_t)4 * VOL + 16) +
        (size_t)(set - 2) * (BATCH * N * N);
    bits[(size_t)(b * N + x) * N + t] = v;
  }

  // exact nearest-zero distances along y
  int carryL = -1000, carryR = 2000;
  #pragma unroll
  for (int cc = 0; cc < 4; ++cc) {
    const int lv = lastZ[cc][z], fv = firstZ[cc][z];
    if (cc < c) carryL = max(carryL, lv);
    if (cc > c) carryR = min(carryR, fv);
  }
  int dl[16];
  {
    int last = carryL;
    #pragma unroll
    for (int k = 0; k < 16; ++k) {
      const int y = 16 * c + k;
      if ((zm >> k) & 1) last = y;
      dl[k] = y - last;
    }
  }
  {
    int first = carryR;
    #pragma unroll
    for (int k = 15; k >= 0; --k) {
      const int y = 16 * c + k;
      if ((zm >> k) & 1) first = y;
      const int d = min(dl[k], first - y);
      Bm[y][z] = (d > 63) ? BIGF : (float)(d * d + z * z);  // + j^2 folded
    }
  }
  __syncthreads();

  // Z-envelope: out[y][zz] = zz^2 + min_j (Bm[y][j] - 2*j*zz)
  {
    const int y = t & 63, w = t >> 6;
    float acc[16], zq[16];
    #pragma unroll
    for (int q = 0; q < 16; ++q) { acc[q] = FBIG; zq[q] = (float)(w + 4 * q); }
    float m2j = 0.f;
    #pragma unroll 4
    for (int j = 0; j < N; ++j) {
      const float fj = Bm[y][j];
      #pragma unroll
      for (int q = 0; q < 16; ++q)
        acc[q] = fminf(acc[q], fmaf(m2j, zq[q], fj));
      m2j -= 2.f;
    }
    #pragma unroll
    for (int q = 0; q < 16; ++q)
      Ao[y][w + 4 * q] = fmaf(zq[q], zq[q], acc[q]);
  }
  __syncthreads();

  float* mid = ws + (size_t)set * VOL;
  #pragma unroll
  for (int k = 0; k < 16; ++k) {
    const int e = t + 256 * k;
    mid[planeBase + e] = Ao[e >> 6][e & 63];
  }
}

// K2: fused double X-envelope (tdm + levelzero of one mask) + hausdorff reduce.
__global__ __launch_bounds__(256) void edt_x_fused(float* __restrict__ ws) {
  __shared__ float A1[N][LP];
  __shared__ float A2[N][LP];
  __shared__ float redS[4], redM[4], redB[4];
  const int m = blockIdx.x >> 7;  // 0: mask1 (tsd1, pairs bnd2); 1: mask2
  const int plane = blockIdx.x & 127;
  const int b = plane >> 6, y = plane & 63;
  const int t = threadIdx.x;
  const int z = t & 63, w = t >> 6;

  const float* mid1 = ws + (size_t)m * VOL;        // tdm mid
  const float* mid2 = ws + (size_t)(2 + m) * VOL;  // level-zero mid
  #pragma unroll
  for (int k = 0; k < 16; ++k) {
    const int e = t + 256 * k;
    const int xx = e >> 6, zz = e & 63;
    const float xs = (float)(xx * xx);
    const size_t idx = (size_t)(b * N + xx) * PLANE + y * N + zz;
    A1[xx][zz] = mid1[idx] + xs;  // + j^2 folded
    A2[xx][zz] = mid2[idx] + xs;
  }
  __syncthreads();

  float a1[16], a2[16], xq[16];
  #pragma unroll
  for (int q = 0; q < 16; ++q) {
    a1[q] = FBIG; a2[q] = FBIG; xq[q] = (float)(w + 4 * q);
  }
  float m2j = 0.f;
  #pragma unroll 2
  for (int j = 0; j < N; ++j) {
    const float f1 = A1[j][z];
    const float f2 = A2[j][z];
    #pragma unroll
    for (int q = 0; q < 16; ++q) {
      a1[q] = fminf(a1[q], fmaf(m2j, xq[q], f1));
      a2[q] = fminf(a2[q], fmaf(m2j, xq[q], f2));
    }
    m2j -= 2.f;
  }

  // epilogue: tsd = sqrt(e_tdm) - sqrt(e_lz0); h = bnd_partner * |tsd|
  const unsigned long long* bits =
      (const unsigned long long*)(ws + (size_t)4 * VOL + 16) +
      (size_t)(m == 0 ? 1 : 0) * (BATCH * N * N);
  float hsum = 0.f, hmax = 0.f, bsum = 0.f;
  #pragma unroll
  for (int q = 0; q < 16; ++q) {
    const float e1 = fmaf(xq[q], xq[q], a1[q]);
    const float e2 = fmaf(xq[q], xq[q], a2[q]);
    const float tsd = sqrtf(e1) - sqrtf(e2);
    const int xx = w + 4 * q;
    const unsigned long long bv = bits[(size_t)(b * N + xx) * N + z];
    const float bnd = (float)((bv >> y) & 1ull);
    const float h = bnd * fabsf(tsd);
    hsum += h; bsum += bnd; hmax = fmaxf(hmax, h);
  }
  #pragma unroll
  for (int o = 32; o > 0; o >>= 1) {
    hsum += __shfl_down(hsum, o);
    bsum += __shfl_down(bsum, o);
    hmax = fmaxf(hmax, __shfl_down(hmax, o));
  }
  if (z == 0) { redS[w] = hsum; redB[w] = bsum; redM[w] = hmax; }
  __syncthreads();
  if (t == 0) {
    float* acc = ws + (size_t)4 * VOL;
    const float s = redS[0] + redS[1] + redS[2] + redS[3];
    const float bs = redB[0] + redB[1] + redB[2] + redB[3];
    const float mx = fmaxf(fmaxf(redM[0], redM[1]), fmaxf(redM[2], redM[3]));
    if (m == 0) {  // tsd1 x bnd2 -> h_outer; count bnd2
      atomicAdd(&acc[3], s);
      atomicAdd(&acc[1], bs);
      atomicMax((int*)&acc[5], __float_as_int(mx));  // vals >= 0
    } else {       // tsd2 x bnd1 -> h_inner; count bnd1
      atomicAdd(&acc[2], s);
      atomicAdd(&acc[0], bs);
      atomicMax((int*)&acc[4], __float_as_int(mx));
    }
  }
}

__global__ void final_k(const float* __restrict__ ws, float* __restrict__ out) {
  if (threadIdx.x == 0) {
    const float* acc = ws + (size_t)4 * VOL;
    const float him = acc[2] / acc[0];
    const float hom = acc[3] / acc[1];
    out[0] = him;
    out[1] = acc[4];
    out[2] = hom;
    out[3] = acc[5];
    out[4] = (him - 2.f) * (him - 2.f) + (hom - 2.f) * (hom - 2.f);
  }
}

extern "C" void kernel_launch(void* const* d_in, const int* in_sizes, int n_in,
                              void* d_out, int out_size, void* d_ws,
                              size_t ws_size, hipStream_t stream) {
  (void)in_sizes; (void)n_in; (void)out_size; (void)ws_size;
  const int* mmap = (const int*)d_in[0];
  float* ws = (float*)d_ws;
  float* out = (float*)d_out;

  edt_yz<<<4 * BATCH * N, 256, 0, stream>>>(mmap, ws);      // 4 Y+Z passes
  edt_x_fused<<<2 * BATCH * N, 256, 0, stream>>>(ws);       // 2x double X-pass
  final_k<<<1, 64, 0, stream>>>(ws, out);
}

// Round 4
// 31.874 us; speedup vs baseline: 3.5058x; 1.4513x over previous
//
#include <hip/hip_runtime.h>
#include <hip/hip_bf16.h>
#include <math.h>

#define N 64
#define BATCH 2
#define PLANE (N * N)            // 4096
#define VOL (BATCH * N * N * N)  // 524288
#define BIGF 1e8f
#define LP 65                    // padded LDS stride
#define FBIG 3.4e38f
#define MASK1 0x17u              // labels {0,1,2,4}
#define MASK2 0x13u              // labels {0,1,4}

// ---------------------------------------------------------------------------
// Workspace (floats):
//   [0, 4*VOL): mid slots — slot m = tdm_m mid, slot 2+m = levelzero_m mid
//   at 4*VOL:   uint64 bits[2][BATCH*N*N]  (boundary y-bitmask per (b,x,z))
//               = 128 KB = 32768 floats
//   at 4*VOL + 32768: float part[256][32]  (per-K2-block partials, 128B apart)
//               part[bid][0]=h_sum, [1]=bnd_sum, [2]=h_max
//   K2 block m = bid>>7:  m=0 -> tsd1 x bnd2 (h_outer); m=1 -> tsd2 x bnd1.
// ---------------------------------------------------------------------------

// K1: per (mask m, b, x)-plane: column bitmasks -> Y-scan (clz/ffs) for both
// tdm and level-zero sets -> two Z-envelopes (2-op inner) -> mids + bnd bits.
__global__ __launch_bounds__(512) void edt_yz(const int* __restrict__ mmap,
                                              float* __restrict__ ws) {
  __shared__ unsigned char colb[3][8][64];     // lz bits: plane, y-chunk, z
  __shared__ unsigned long long colm[3][64];   // column masks per plane, z
  __shared__ unsigned long long zmT[64];       // tdm zero-sites per z
  __shared__ unsigned long long zmL[64];       // levelzero zero-sites per z
  __shared__ float Bm1[N][LP];
  __shared__ float Bm2[N][LP];
  const int m = blockIdx.x >> 7;
  const int plane = blockIdx.x & 127;
  const int b = plane >> 6, x = plane & 63;
  const int t = threadIdx.x;
  const int z = t & 63, c = t >> 6;            // chunk c: y in [8c, 8c+8)
  const unsigned lmask = m ? MASK2 : MASK1;
  const size_t bbase = (size_t)(b * N) * PLANE;

  // ---- load 3 planes' lz bits (x-1, x, x+1) ----
  #pragma unroll
  for (int p = 0; p < 3; ++p) {
    const int xp = x + p - 1;
    unsigned byte = 0;
    if (xp >= 0 && xp < N) {
      const size_t pb = bbase + (size_t)xp * PLANE;
      #pragma unroll
      for (int k = 0; k < 8; ++k) {
        const int y = 8 * c + k;
        byte |= ((lmask >> mmap[pb + y * N + z]) & 1u) << k;
      }
    }
    colb[p][c][z] = (unsigned char)byte;
  }
  __syncthreads();
  if (t < 192) {
    const int p = t >> 6, zz = t & 63;
    unsigned long long v = 0;
    #pragma unroll
    for (int cc = 0; cc < 8; ++cc)
      v |= (unsigned long long)colb[p][cc][zz] << (8 * cc);
    colm[p][zz] = v;
  }
  __syncthreads();
  // ---- derive zero-site masks + boundary bits (one thread per z) ----
  if (t < 64) {
    const unsigned long long cx = colm[1][t];
    unsigned long long nb = colm[0][t] | colm[2][t] | (cx << 1) | (cx >> 1);
    if (t > 0) nb |= colm[1][t - 1];
    if (t < 63) nb |= colm[1][t + 1];
    zmT[t] = ~cx;        // tdm EDT zero-set: lz==0
    zmL[t] = cx | nb;    // levelzero EDT zero-set: lz | dilation
    unsigned long long* bits =
        (unsigned long long*)(ws + (size_t)4 * VOL) + (size_t)m * (BATCH * N * N);
    bits[(size_t)(b * N + x) * N + t] = nb & ~cx;  // boundary: b==1
  }
  __syncthreads();

  // ---- exact Y-scan via clz/ffs on 64-bit column masks (+z^2 folded) ----
  {
    const unsigned long long M0 = zmT[z];
    const unsigned long long M1 = zmL[z];
    const float zs = (float)(z * z);
    #pragma unroll
    for (int k = 0; k < 8; ++k) {
      const int y = 8 * c + k;
      {
        const unsigned long long lo = M0 << (63 - y);
        const int dl = __clzll((long long)lo);
        const int f = __ffsll((long long)(M0 >> y));
        const int d = min(dl, f ? (f - 1) : 99);
        Bm1[y][z] = (d > 63) ? BIGF : (float)(d * d) + zs;
      }
      {
        const unsigned long long lo = M1 << (63 - y);
        const int dl = __clzll((long long)lo);
        const int f = __ffsll((long long)(M1 >> y));
        const int d = min(dl, f ? (f - 1) : 99);
        Bm2[y][z] = (d > 63) ? BIGF : (float)(d * d) + zs;
      }
    }
  }
  __syncthreads();

  // ---- two Z-envelopes, interleaved: out = zz^2 + min_j (Bm[j] - 2 j zz) ----
  const int y = t & 63, w = t >> 6;
  float a1[8], a2[8], zq[8];
  #pragma unroll
  for (int q = 0; q < 8; ++q) { a1[q] = FBIG; a2[q] = FBIG; zq[q] = (float)(w + 8 * q); }
  float m2j = 0.f;
  #pragma unroll 2
  for (int j = 0; j < N; ++j) {
    const float f1 = Bm1[y][j];
    const float f2 = Bm2[y][j];
    #pragma unroll
    for (int q = 0; q < 8; ++q) {
      a1[q] = fminf(a1[q], fmaf(m2j, zq[q], f1));
      a2[q] = fminf(a2[q], fmaf(m2j, zq[q], f2));
    }
    m2j -= 2.f;
  }
  __syncthreads();  // all reads of Bm done before overwrite
  #pragma unroll
  for (int q = 0; q < 8; ++q) {
    Bm1[y][w + 8 * q] = fmaf(zq[q], zq[q], a1[q]);
    Bm2[y][w + 8 * q] = fmaf(zq[q], zq[q], a2[q]);
  }
  __syncthreads();
  float* mid1 = ws + (size_t)m * VOL;
  float* mid2 = ws + (size_t)(2 + m) * VOL;
  const size_t pbase = (size_t)(b * N + x) * PLANE;
  #pragma unroll
  for (int k = 0; k < 8; ++k) {
    const int e = t + 512 * k;
    mid1[pbase + e] = Bm1[e >> 6][e & 63];
    mid2[pbase + e] = Bm2[e >> 6][e & 63];
  }
}

// K2: fused double X-envelope (tdm + levelzero of mask m) + hausdorff partials.
__global__ __launch_bounds__(256) void edt_x_fused(float* __restrict__ ws) {
  __shared__ float A1[N][LP];
  __shared__ float A2[N][LP];
  __shared__ float redS[4], redM[4], redB[4];
  const int m = blockIdx.x >> 7;  // 0: tsd1 (pairs bnd2); 1: tsd2 (pairs bnd1)
  const int plane = blockIdx.x & 127;
  const int b = plane >> 6, y = plane & 63;
  const int t = threadIdx.x;
  const int z = t & 63, w = t >> 6;

  const float* mid1 = ws + (size_t)m * VOL;        // tdm mid
  const float* mid2 = ws + (size_t)(2 + m) * VOL;  // levelzero mid
  #pragma unroll
  for (int k = 0; k < 16; ++k) {
    const int e = t + 256 * k;
    const int xx = e >> 6, zz = e & 63;
    const float xs = (float)(xx * xx);
    const size_t idx = (size_t)(b * N + xx) * PLANE + y * N + zz;
    A1[xx][zz] = mid1[idx] + xs;  // + j^2 folded
    A2[xx][zz] = mid2[idx] + xs;
  }
  __syncthreads();

  float a1[16], a2[16], xq[16];
  #pragma unroll
  for (int q = 0; q < 16; ++q) { a1[q] = FBIG; a2[q] = FBIG; xq[q] = (float)(w + 4 * q); }
  float m2j = 0.f;
  #pragma unroll 2
  for (int j = 0; j < N; ++j) {
    const float f1 = A1[j][z];
    const float f2 = A2[j][z];
    #pragma unroll
    for (int q = 0; q < 16; ++q) {
      a1[q] = fminf(a1[q], fmaf(m2j, xq[q], f1));
      a2[q] = fminf(a2[q], fmaf(m2j, xq[q], f2));
    }
    m2j -= 2.f;
  }

  // epilogue: tsd = sqrt(e_tdm) - sqrt(e_lz0); h = bnd_partner * |tsd|
  const unsigned long long* bits =
      (const unsigned long long*)(ws + (size_t)4 * VOL) +
      (size_t)(m == 0 ? 1 : 0) * (BATCH * N * N);
  float hsum = 0.f, hmax = 0.f, bsum = 0.f;
  #pragma unroll
  for (int q = 0; q < 16; ++q) {
    const float e1 = fmaf(xq[q], xq[q], a1[q]);
    const float e2 = fmaf(xq[q], xq[q], a2[q]);
    const float tsd = sqrtf(e1) - sqrtf(e2);
    const int xx = w + 4 * q;
    const unsigned long long bv = bits[(size_t)(b * N + xx) * N + z];
    const float bnd = (float)((bv >> y) & 1ull);
    const float h = bnd * fabsf(tsd);
    hsum += h; bsum += bnd; hmax = fmaxf(hmax, h);
  }
  #pragma unroll
  for (int o = 32; o > 0; o >>= 1) {
    hsum += __shfl_down(hsum, o);
    bsum += __shfl_down(bsum, o);
    hmax = fmaxf(hmax, __shfl_down(hmax, o));
  }
  if (z == 0) { redS[w] = hsum; redB[w] = bsum; redM[w] = hmax; }
  __syncthreads();
  if (t == 0) {
    float* part = ws + (size_t)4 * VOL + 32768 + (size_t)blockIdx.x * 32;
    part[0] = redS[0] + redS[1] + redS[2] + redS[3];
    part[1] = redB[0] + redB[1] + redB[2] + redB[3];
    part[2] = fmaxf(fmaxf(redM[0], redM[1]), fmaxf(redM[2], redM[3]));
  }
}

// K3: reduce 256 per-block partials -> 5 outputs. Blocks 0..127 were m=0
// (h_outer, bnd2), 128..255 were m=1 (h_inner, bnd1).
__global__ __launch_bounds__(256) void final_k(const float* __restrict__ ws,
                                               float* __restrict__ out) {
  __shared__ float Ls[4], Lb[4], Lm[4];
  const int t = threadIdx.x;
  const float* part = ws + (size_t)4 * VOL + 32768;
  float s = part[(size_t)t * 32 + 0];
  float bsum = part[(size_t)t * 32 + 1];
  float mx = part[(size_t)t * 32 + 2];
  #pragma unroll
  for (int o = 32; o > 0; o >>= 1) {
    s += __shfl_down(s, o);
    bsum += __shfl_down(bsum, o);
    mx = fmaxf(mx, __shfl_down(mx, o));
  }
  const int wv = t >> 6;
  if ((t & 63) == 0) { Ls[wv] = s; Lb[wv] = bsum; Lm[wv] = mx; }
  __syncthreads();
  if (t == 0) {
    const float s_ho = Ls[0] + Ls[1], b2 = Lb[0] + Lb[1];
    const float mho = fmaxf(Lm[0], Lm[1]);
    const float s_hi = Ls[2] + Ls[3], b1 = Lb[2] + Lb[3];
    const float mhi = fmaxf(Lm[2], Lm[3]);
    const float him = s_hi / b1;
    const float hom = s_ho / b2;
    out[0] = him;
    out[1] = mhi;
    out[2] = hom;
    out[3] = mho;
    out[4] = (him - 2.f) * (him - 2.f) + (hom - 2.f) * (hom - 2.f);
  }
}

extern "C" void kernel_launch(void* const* d_in, const int* in_sizes, int n_in,
                              void* d_out, int out_size, void* d_ws,
                              size_t ws_size, hipStream_t stream) {
  (void)in_sizes; (void)n_in; (void)out_size; (void)ws_size;
  const int* mmap = (const int*)d_in[0];
  float* ws = (float*)d_ws;
  float* out = (float*)d_out;

  edt_yz<<<2 * BATCH * N, 512, 0, stream>>>(mmap, ws);   // 2 fused YZ blocks/plane
  edt_x_fused<<<2 * BATCH * N, 256, 0, stream>>>(ws);    // 2 fused double X-pass
  final_k<<<1, 256, 0, stream>>>(ws, out);
}

// Round 5
// 31.744 us; speedup vs baseline: 3.5202x; 1.0041x over previous
//
#include <hip/hip_runtime.h>
#include <hip/hip_bf16.h>
#include <math.h>

#define N 64
#define BATCH 2
#define PLANE (N * N)            // 4096
#define VOL (BATCH * N * N * N)  // 524288 elements per slot
#define BIGF 1e8f
#define LP 65                    // padded LDS stride
#define FBIG 3.4e38f
#define MASK1 0x17u              // labels {0,1,2,4}
#define MASK2 0x13u              // labels {0,1,4}

// ---------------------------------------------------------------------------
// Workspace (bytes):
//   [0, 8*VOL): ushort mids, 4 slots x VOL — slot m = tdm_m, slot 2+m = lz0_m
//              (exact: values <= 7938; 65535 = BIG sentinel)
//   at 8*VOL:             uint64 bits[2][BATCH*N*N]   (boundary y-bitmasks)
//   at 8*VOL + 131072:    float part[256][8]          (per-K2-block partials)
//   at 8*VOL + 131072 + 8192: int cnt                 (K2 completion counter)
// K2 block m = bid>>7:  m=0 -> tsd1 x bnd2 (h_outer); m=1 -> tsd2 x bnd1.
// ---------------------------------------------------------------------------

#define BITS_OFF ((size_t)8 * VOL)
#define PART_OFF (BITS_OFF + (size_t)2 * BATCH * N * N * 8)
#define CNT_OFF (PART_OFF + (size_t)256 * 8 * 4)

// K1: per (mask m, b, x)-plane: column bitmasks -> exact Y-scan (clz/ffs) for
// tdm + level-zero sets -> two Z-envelopes (2-op inner) -> ushort mids + bits.
__global__ __launch_bounds__(512) void edt_yz(const int* __restrict__ mmap,
                                              void* __restrict__ wsv) {
  __shared__ unsigned char colb[3][8][64];     // lz bits: plane, y-chunk, z
  __shared__ unsigned long long colm[3][64];   // column masks per plane, z
  __shared__ unsigned long long zmT[64];       // tdm zero-sites per z
  __shared__ unsigned long long zmL[64];       // levelzero zero-sites per z
  __shared__ float Bm1[N][LP];
  __shared__ float Bm2[N][LP];
  const int m = blockIdx.x >> 7;
  const int plane = blockIdx.x & 127;
  const int b = plane >> 6, x = plane & 63;
  const int t = threadIdx.x;
  const int z = t & 63, c = t >> 6;            // chunk c: y in [8c, 8c+8)
  const unsigned lmask = m ? MASK2 : MASK1;
  const size_t bbase = (size_t)(b * N) * PLANE;

  if (blockIdx.x == 0 && t == 0) *(int*)((char*)wsv + CNT_OFF) = 0;

  // ---- load 3 planes' lz bits (x-1, x, x+1) ----
  #pragma unroll
  for (int p = 0; p < 3; ++p) {
    const int xp = x + p - 1;
    unsigned byte = 0;
    if (xp >= 0 && xp < N) {
      const size_t pb = bbase + (size_t)xp * PLANE;
      #pragma unroll
      for (int k = 0; k < 8; ++k) {
        const int y = 8 * c + k;
        byte |= ((lmask >> mmap[pb + y * N + z]) & 1u) << k;
      }
    }
    colb[p][c][z] = (unsigned char)byte;
  }
  __syncthreads();
  if (t < 192) {
    const int p = t >> 6, zz = t & 63;
    unsigned long long v = 0;
    #pragma unroll
    for (int cc = 0; cc < 8; ++cc)
      v |= (unsigned long long)colb[p][cc][zz] << (8 * cc);
    colm[p][zz] = v;
  }
  __syncthreads();
  // ---- derive zero-site masks + boundary bits (one thread per z) ----
  if (t < 64) {
    const unsigned long long cx = colm[1][t];
    unsigned long long nb = colm[0][t] | colm[2][t] | (cx << 1) | (cx >> 1);
    if (t > 0) nb |= colm[1][t - 1];
    if (t < 63) nb |= colm[1][t + 1];
    zmT[t] = ~cx;        // tdm EDT zero-set: lz==0
    zmL[t] = cx | nb;    // levelzero EDT zero-set: lz | dilation
    unsigned long long* bits =
        (unsigned long long*)((char*)wsv + BITS_OFF) + (size_t)m * (BATCH * N * N);
    bits[(size_t)(b * N + x) * N + t] = nb & ~cx;  // boundary: b==1
  }
  __syncthreads();

  // ---- exact Y-scan via clz/ffs on 64-bit column masks (+z^2 folded) ----
  {
    const unsigned long long M0 = zmT[z];
    const unsigned long long M1 = zmL[z];
    const float zs = (float)(z * z);
    #pragma unroll
    for (int k = 0; k < 8; ++k) {
      const int y = 8 * c + k;
      {
        const unsigned long long lo = M0 << (63 - y);
        const int dl = __clzll((long long)lo);
        const int f = __ffsll((long long)(M0 >> y));
        const int d = min(dl, f ? (f - 1) : 99);
        Bm1[y][z] = (d > 63) ? BIGF : (float)(d * d) + zs;
      }
      {
        const unsigned long long lo = M1 << (63 - y);
        const int dl = __clzll((long long)lo);
        const int f = __ffsll((long long)(M1 >> y));
        const int d = min(dl, f ? (f - 1) : 99);
        Bm2[y][z] = (d > 63) ? BIGF : (float)(d * d) + zs;
      }
    }
  }
  __syncthreads();

  // ---- two Z-envelopes, interleaved: out = zz^2 + min_j (Bm[j] - 2 j zz) ----
  const int y = t & 63, w = t >> 6;
  float a1[8], a2[8], zq[8];
  #pragma unroll
  for (int q = 0; q < 8; ++q) { a1[q] = FBIG; a2[q] = FBIG; zq[q] = (float)(w + 8 * q); }
  float m2j = 0.f;
  #pragma unroll 2
  for (int j = 0; j < N; ++j) {
    const float f1 = Bm1[y][j];
    const float f2 = Bm2[y][j];
    #pragma unroll
    for (int q = 0; q < 8; ++q) {
      a1[q] = fminf(a1[q], fmaf(m2j, zq[q], f1));
      a2[q] = fminf(a2[q], fmaf(m2j, zq[q], f2));
    }
    m2j -= 2.f;
  }
  __syncthreads();  // all reads of Bm done before overwrite
  #pragma unroll
  for (int q = 0; q < 8; ++q) {
    Bm1[y][w + 8 * q] = fmaf(zq[q], zq[q], a1[q]);
    Bm2[y][w + 8 * q] = fmaf(zq[q], zq[q], a2[q]);
  }
  __syncthreads();
  unsigned short* mid1 = (unsigned short*)wsv + (size_t)m * VOL;
  unsigned short* mid2 = (unsigned short*)wsv + (size_t)(2 + m) * VOL;
  const size_t pbase = (size_t)(b * N + x) * PLANE;
  #pragma unroll
  for (int k = 0; k < 8; ++k) {
    const int e = t + 512 * k;
    mid1[pbase + e] = (unsigned short)fminf(Bm1[e >> 6][e & 63], 65535.f);
    mid2[pbase + e] = (unsigned short)fminf(Bm2[e >> 6][e & 63], 65535.f);
  }
}

// K2: fused double X-envelope (tdm + levelzero of mask m) + hausdorff partials
// + last-block final reduction straight into d_out.
__global__ __launch_bounds__(512) void edt_x_fused(void* __restrict__ wsv,
                                                   float* __restrict__ out) {
  __shared__ float A1[N][LP];
  __shared__ float A2[N][LP];
  __shared__ float redS[8], redM[8], redB[8];
  __shared__ int lastFlag;
  const int m = blockIdx.x >> 7;  // 0: tsd1 (pairs bnd2); 1: tsd2 (pairs bnd1)
  const int plane = blockIdx.x & 127;
  const int b = plane >> 6, y = plane & 63;
  const int t = threadIdx.x;
  const int z = t & 63, w = t >> 6;  // w in [0,8)

  const unsigned short* mid1 = (const unsigned short*)wsv + (size_t)m * VOL;
  const unsigned short* mid2 = (const unsigned short*)wsv + (size_t)(2 + m) * VOL;
  #pragma unroll
  for (int k = 0; k < 8; ++k) {
    const int e = t + 512 * k;
    const int xx = e >> 6, zz = e & 63;
    const float xs = (float)(xx * xx);
    const size_t idx = (size_t)(b * N + xx) * PLANE + y * N + zz;
    const unsigned v1 = mid1[idx];
    const unsigned v2 = mid2[idx];
    A1[xx][zz] = ((v1 == 65535u) ? BIGF : (float)v1) + xs;  // + j^2 folded
    A2[xx][zz] = ((v2 == 65535u) ? BIGF : (float)v2) + xs;
  }
  __syncthreads();

  float a1[8], a2[8], xq[8];
  #pragma unroll
  for (int q = 0; q < 8; ++q) { a1[q] = FBIG; a2[q] = FBIG; xq[q] = (float)(w + 8 * q); }
  float m2j = 0.f;
  #pragma unroll 2
  for (int j = 0; j < N; ++j) {
    const float f1 = A1[j][z];
    const float f2 = A2[j][z];
    #pragma unroll
    for (int q = 0; q < 8; ++q) {
      a1[q] = fminf(a1[q], fmaf(m2j, xq[q], f1));
      a2[q] = fminf(a2[q], fmaf(m2j, xq[q], f2));
    }
    m2j -= 2.f;
  }

  // epilogue: tsd = sqrt(e_tdm) - sqrt(e_lz0); h = bnd_partner * |tsd|
  const unsigned long long* bits =
      (const unsigned long long*)((char*)wsv + BITS_OFF) +
      (size_t)(m == 0 ? 1 : 0) * (BATCH * N * N);
  float hsum = 0.f, hmax = 0.f, bsum = 0.f;
  #pragma unroll
  for (int q = 0; q < 8; ++q) {
    const float e1 = fmaf(xq[q], xq[q], a1[q]);
    const float e2 = fmaf(xq[q], xq[q], a2[q]);
    const float tsd = sqrtf(e1) - sqrtf(e2);
    const int xx = w + 8 * q;
    const unsigned long long bv = bits[(size_t)(b * N + xx) * N + z];
    const float bnd = (float)((bv >> y) & 1ull);
    const float h = bnd * fabsf(tsd);
    hsum += h; bsum += bnd; hmax = fmaxf(hmax, h);
  }
  #pragma unroll
  for (int o = 32; o > 0; o >>= 1) {
    hsum += __shfl_down(hsum, o);
    bsum += __shfl_down(bsum, o);
    hmax = fmaxf(hmax, __shfl_down(hmax, o));
  }
  if (z == 0) { redS[w] = hsum; redB[w] = bsum; redM[w] = hmax; }
  __syncthreads();

  float* part = (float*)((char*)wsv + PART_OFF);
  int* cnt = (int*)((char*)wsv + CNT_OFF);
  if (t == 0) {
    float s = 0.f, bs = 0.f, mx = 0.f;
    #pragma unroll
    for (int i = 0; i < 8; ++i) {
      s += redS[i]; bs += redB[i]; mx = fmaxf(mx, redM[i]);
    }
    float* p = part + (size_t)blockIdx.x * 8;
    p[0] = s; p[1] = bs; p[2] = mx;
    __threadfence();
    const int old = atomicAdd(cnt, 1);
    lastFlag = (old == 255) ? 1 : 0;
  }
  __syncthreads();
  if (lastFlag) {
    __threadfence();  // acquire: other blocks' part[] stores
    float s = 0.f, bs = 0.f, mx = 0.f;
    if (t < 256) {
      const float* p = part + (size_t)t * 8;
      s = p[0]; bs = p[1]; mx = p[2];
    }
    #pragma unroll
    for (int o = 32; o > 0; o >>= 1) {
      s += __shfl_down(s, o);
      bs += __shfl_down(bs, o);
      mx = fmaxf(mx, __shfl_down(mx, o));
    }
    __syncthreads();  // red arrays reuse
    if ((t & 63) == 0 && t < 256) {
      redS[t >> 6] = s; redB[t >> 6] = bs; redM[t >> 6] = mx;
    }
    __syncthreads();
    if (t == 0) {
      // partial idx p<128 -> m=0 (h_outer, bnd2) -> waves 0,1
      const float s_ho = redS[0] + redS[1], b2 = redB[0] + redB[1];
      const float mho = fmaxf(redM[0], redM[1]);
      const float s_hi = redS[2] + redS[3], b1 = redB[2] + redB[3];
      const float mhi = fmaxf(redM[2], redM[3]);
      const float him = s_hi / b1;
      const float hom = s_ho / b2;
      out[0] = him;
      out[1] = mhi;
      out[2] = hom;
      out[3] = mho;
      out[4] = (him - 2.f) * (him - 2.f) + (hom - 2.f) * (hom - 2.f);
    }
  }
}

extern "C" void kernel_launch(void* const* d_in, const int* in_sizes, int n_in,
                              void* d_out, int out_size, void* d_ws,
                              size_t ws_size, hipStream_t stream) {
  (void)in_sizes; (void)n_in; (void)out_size; (void)ws_size;
  const int* mmap = (const int*)d_in[0];
  float* out = (float*)d_out;

  edt_yz<<<2 * BATCH * N, 512, 0, stream>>>(mmap, d_ws);
  edt_x_fused<<<2 * BATCH * N, 512, 0, stream>>>(d_ws, out);
}